// Round 12
// baseline (97.541 us; speedup 1.0000x reference)
//
#include <hip/hip_runtime.h>
#include <hip/hip_bf16.h>
#include <math.h>

// SupCon loss, N=8192 D=128 fp32 in, scalar fp32 out.
// Round 15: R14's software pipeline was the first live lever on sim's latency
// wall (dur 102.4 -> 97.4, no spill). Deeper buffering would spill (audit:
// 227+32 > 256-reg cap at 2 waves/SIMD; three prior spill episodes at lower
// estimates), so this round deepens ILP register-neutrally and cuts launches:
// (a) rebalanced 2-buffer schedule -- next tile's kk0 AND kk1 are both issued
//     before the epilogue (bfB frees after its last MFMA), so 2 of 4 kk-steps
//     get ~600-cyc epilogue cover instead of 1 (R14 left kk1 with ~78 cyc).
// (b) zero_kernel removed: prep zeroes out[0]; reduce builds the label
//     histogram in its own LDS (8192 coalesced reads + LDS atomics per block,
//     parallel across 128 blocks). prep drops global hist atomics. 4 -> 3
//     launches.
// Everything else R14-verbatim (full matrix, 256 thr/4 waves, no LDS/barriers/
// atomics in sim, fragment-major FbP in L2, private partial slots).

constexpr int N = 8192;
constexpr int D = 128;

typedef __attribute__((ext_vector_type(8))) short short8;  // 8 bf16 = 4 VGPRs
typedef __attribute__((ext_vector_type(4))) float f32x4;

constexpr float SELF_POISON = -50.0f;  // exp2(-50) ~ 9e-16; |s2| <= 14.43 real

__device__ __forceinline__ float fast_exp2(float x) {
#if __has_builtin(__builtin_amdgcn_exp2f)
    return __builtin_amdgcn_exp2f(x);
#else
    return __expf(x * 0.69314718056f);
#endif
}

// ---------------- prep: bf16 rows scaled into log2 domain, fragment layout --
// FbP uint index for element pair (row, k=2l): (row>>4)*1024 + (l>>2)*64 +
// (row&15)*4 + (l&3). Chunk chi = l>>2 holds k = 8*chi .. 8*chi+7 in order.
// Also zeroes out[0] (stream-ordered before reduce's atomicAdd).
__global__ void prep_kernel(const float* __restrict__ F,
                            unsigned int* __restrict__ FbP,
                            float* __restrict__ out) {
    if (blockIdx.x == 0 && threadIdx.x == 0) out[0] = 0.0f;
    int row = blockIdx.x * 4 + (threadIdx.x >> 6);
    int l = threadIdx.x & 63;
    float2 v = ((const float2*)(F + (size_t)row * D))[l];
    float ss = v.x * v.x + v.y * v.y;
#pragma unroll
    for (int off = 32; off > 0; off >>= 1) ss += __shfl_xor(ss, off);
    float sc = sqrtf(14.4269504089f / ss);  // 10 * log2(e), folded
    __hip_bfloat16 hx = __float2bfloat16(v.x * sc);
    __hip_bfloat16 hy = __float2bfloat16(v.y * sc);
    unsigned int ux = *(unsigned short*)&hx;
    unsigned int uy = *(unsigned short*)&hy;
    unsigned int idx = ((unsigned)(row >> 4) << 10) | ((unsigned)(l >> 2) << 6) |
                       ((unsigned)(row & 15) << 2) | (unsigned)(l & 3);
    FbP[idx] = ux | (uy << 16);
}

// ---------------- sim: full matrix, MFMA, no LDS/barriers/atomics -----------
// Block (ti, g): A-frags for row-tile ti in registers; B-tiles tj in
// [4g, 4g+3] streamed from L2 with a rebalanced 1-deep software pipeline:
// entering each tile, kk0 and kk1 are already in flight (issued before the
// previous tile's epilogue).
#define LOADB(BUF, TJ, KK)                                          \
    _Pragma("unroll") for (int n_ = 0; n_ < 4; ++n_)                \
        BUF[n_] = P[((TJ) * 8 + wx * 4 + n_) * 256 + (KK) * 64 + l];

#define MFMASTEP(BUF, KK)                                           \
    _Pragma("unroll") for (int m_ = 0; m_ < 4; ++m_)                \
        _Pragma("unroll") for (int n_ = 0; n_ < 4; ++n_)            \
            acc[m_][n_] = __builtin_amdgcn_mfma_f32_16x16x32_bf16(  \
                Af[KK][m_], BUF[n_], acc[m_][n_], 0, 0, 0);

__global__ __launch_bounds__(256, 2) void sim_kernel(
    const short8* __restrict__ P, const int* __restrict__ labels,
    float* __restrict__ partE, float* __restrict__ partP) {
    const int ti = blockIdx.x >> 4;   // 64 row tiles
    const int g  = blockIdx.x & 15;   // 16 column groups
    const int tjs = g * 4;
    const int i0 = ti * 128;

    const int t = threadIdx.x, w = t >> 6, l = t & 63;
    const int c = l & 15, quad = l >> 4;    // MFMA lane split
    const int wy = w >> 1, wx = w & 1;      // 64x64 quadrant per wave

    // A fragments for the whole strip: 16 x 1KB coalesced loads, 64 VGPR.
    short8 Af[4][4];  // [kk][m]
#pragma unroll
    for (int kk = 0; kk < 4; ++kk)
#pragma unroll
        for (int m = 0; m < 4; ++m)
            Af[kk][m] = P[(ti * 8 + wy * 4 + m) * 256 + kk * 64 + l];

    // row labels for this wave's rows (strip-constant)
    int li[4][4];
#pragma unroll
    for (int m = 0; m < 4; ++m)
#pragma unroll
        for (int r = 0; r < 4; ++r)
            li[m][r] = labels[i0 + wy * 64 + m * 16 + quad * 4 + r];

    const bool selfQuad = (quad == (c >> 2));  // lane may hold self elements

    float RE[4][4] = {}, RP[4][4] = {};  // row partials, carried across strip

    short8 bfA[4], bfB[4];   // B-fragment double buffer (static indices only)
    LOADB(bfA, tjs, 0);      // prologue: kk0 and kk1 of first tile in flight
    LOADB(bfB, tjs, 1);

#pragma unroll 1
    for (int tj = tjs; tj < tjs + 4; ++tj) {
        const int j0 = tj * 128;
        int lj[4];
#pragma unroll
        for (int n = 0; n < 4; ++n) lj[n] = labels[j0 + wx * 64 + n * 16 + c];

        f32x4 acc[4][4] = {};
        const int tp = (tj < tjs + 3) ? tj + 1 : tjs;  // last prefetch harmless
        // steady state: bfA=kk0, bfB=kk1 already in flight (epilogue-covered)
        MFMASTEP(bfA, 0);
        LOADB(bfA, tj, 2);
        MFMASTEP(bfB, 1);
        LOADB(bfB, tj, 3);
        MFMASTEP(bfA, 2);
        LOADB(bfA, tp, 0);
        MFMASTEP(bfB, 3);
        LOADB(bfB, tp, 1);   // next tile's kk1 also rides under the epilogue

        // Diagonal tile: poison self elements so the clean epilogue naturally
        // zeroes them (exp2(-50)~0; the -50 entering RP is corrected at store).
        if (tj == ti && wy == wx) {
#pragma unroll
            for (int m = 0; m < 4; ++m)
#pragma unroll
                for (int r = 0; r < 4; ++r) {
                    bool cond = selfQuad && (r == (c & 3));
                    acc[m][m][r] = cond ? SELF_POISON : acc[m][m][r];
                }
        }

        // ---- minimal row-only epilogue: 5 insts per element ----
        // (covers the latency of the two next-tile prefetches above)
#pragma unroll
        for (int m = 0; m < 4; ++m) {
#pragma unroll
            for (int n = 0; n < 4; ++n) {
#pragma unroll
                for (int r = 0; r < 4; ++r) {
                    float s2 = acc[m][n][r];
                    RE[m][r] += fast_exp2(s2);
                    RP[m][r] += (li[m][r] == lj[n]) ? s2 : 0.0f;
                }
            }
        }
    }

    // strip end: row reduction across the 16 col-lanes, then PLAIN STORES to
    // this block+wave's private slice. No atomics anywhere in this kernel.
#pragma unroll
    for (int m = 0; m < 4; ++m)
#pragma unroll
        for (int r = 0; r < 4; ++r) {
#pragma unroll
            for (int off = 1; off < 16; off <<= 1) {
                RE[m][r] += __shfl_xor(RE[m][r], off);
                RP[m][r] += __shfl_xor(RP[m][r], off);
            }
        }
    if (c == 0) {
        // undo the diag poison injected into the positive-sums: exactly one
        // -50 per (m,r) row group in waves wy==wx of diag-containing blocks.
        if (g == (ti >> 2) && wy == wx) {
#pragma unroll
            for (int m = 0; m < 4; ++m)
#pragma unroll
                for (int r = 0; r < 4; ++r) RP[m][r] -= SELF_POISON;
        }
        const int slot = g * 2 + wx;  // 32 private slots per row
#pragma unroll
        for (int m = 0; m < 4; ++m)
#pragma unroll
            for (int r = 0; r < 4; ++r) {
                int gi = i0 + wy * 64 + m * 16 + quad * 4 + r;
                partE[(size_t)gi * 32 + slot] = RE[m][r];
                partP[(size_t)gi * 32 + slot] = RP[m][r];
            }
    }
}

// ---------------- reduce: 128 blocks; one row per 32-lane half-wave ---------
// Builds the label histogram in LDS (replaces zero_kernel + prep atomics),
// sums the 32 partials per row, one scaled atomicAdd per block into out[0].
__global__ void reduce_kernel(const float* __restrict__ partE,
                              const float* __restrict__ partP,
                              const int* __restrict__ labels,
                              float* __restrict__ out) {
    __shared__ int hist[1024];
    __shared__ float ws4[4];
    const int t = threadIdx.x, w = t >> 6, l = t & 63;
    const int half = l >> 5, sl = l & 31;
    const int rbase = blockIdx.x * 64 + w * 16;  // 64 rows/block, 16/wave

#pragma unroll
    for (int k = 0; k < 4; ++k) hist[t + 256 * k] = 0;
    __syncthreads();
#pragma unroll
    for (int k = 0; k < 32; ++k) atomicAdd(&hist[labels[t + 256 * k]], 1);
    __syncthreads();

    float a = 0.0f;
#pragma unroll
    for (int it = 0; it < 8; ++it) {
        int row = rbase + it * 2 + half;
        float se = partE[(size_t)row * 32 + sl];
        float sp = partP[(size_t)row * 32 + sl];
#pragma unroll
        for (int off = 1; off < 32; off <<= 1) {
            se += __shfl_xor(se, off);
            sp += __shfl_xor(sp, off);
        }
        if (sl == 0) {
            int cnt = hist[labels[row]] - 1;
            if (cnt > 0)
                a += logf(se + 1e-9f) - 0.69314718056f * sp / (float)cnt;
        }
    }
    // wave reduce (only lanes sl==0 carry nonzero a)
#pragma unroll
    for (int off = 1; off < 64; off <<= 1) a += __shfl_xor(a, off);
    if (l == 0) ws4[w] = a;
    __syncthreads();
    if (t == 0) {
        float s = ws4[0] + ws4[1] + ws4[2] + ws4[3];
        atomicAdd(out, s * (1.0f / (float)N));
    }
}

extern "C" void kernel_launch(void* const* d_in, const int* in_sizes, int n_in,
                              void* d_out, int out_size, void* d_ws, size_t ws_size,
                              hipStream_t stream) {
    const float* F      = (const float*)d_in[0];
    const int*   labels = (const int*)d_in[1];
    float* out = (float*)d_out;

    unsigned int* FbP = (unsigned int*)d_ws;                         // 2 MB
    float* partE = (float*)((char*)d_ws + (size_t)2 * 1024 * 1024);  // 1 MB
    float* partP = partE + (size_t)N * 32;                           // 1 MB

    prep_kernel<<<N / 4, 256, 0, stream>>>(F, FbP, out);
    sim_kernel<<<64 * 16, 256, 0, stream>>>((const short8*)FbP, labels, partE,
                                            partP);
    reduce_kernel<<<128, 256, 0, stream>>>(partE, partP, labels, out);
}